// Round 11
// baseline (364.113 us; speedup 1.0000x reference)
//
#include <hip/hip_runtime.h>

#define TSTEPS 512
#define NB     16        // batch per workgroup
#define NW     13        // waves = M-tiles (200 gate-rows -> 13 tiles of 16)
#define WGS    (NW * 64) // 832

typedef _Float16 f16x8 __attribute__((ext_vector_type(8)));
typedef float    f32x4 __attribute__((ext_vector_type(4)));

#define NKF  4           // kfrags per parity buffer (layer1 reads all 4, layer0 kf0-1)
#define PARF 2048        // f16 per parity buffer = 4*64*8

// K row space per parity buffer (4 kfrags x 32 rows = 128), single-f16 h:
//   rows  0-49 : h0(t)     rows 50-54 : x(t+1)    row 55 : pad
//   rows 56-105: h1(t-1)   rows 106-127 : pad (A = 0)
// Weights pre-scaled: gates i,f,o by -log2(e); gate g by 2*log2(e).
// Combined-rcp activations: 5 exp2 + 3 rcp per update.
//
// MERGED-REGION schedule, ONE barrier per region (= per timestep):
//   region r (p=r&1): read buf[p] = {h0(r), x(r+1), h1(r-1)}
//     B(r):   A1 x kf0-3 -> h1(r)   -> buf[p^1] rows 56-105   (2+2 split chains)
//     A(r+1): A0 x kf0-1 -> h0(r+1) -> buf[p^1] rows 0-49
//     xwrite: x(r+2)               -> buf[p^1] rows 50-54
//   s_waitcnt lgkmcnt(0); s_barrier      <-- lgkm-only: the in-flight x global
//     load is NOT drained (__syncthreads would vmcnt(0)-drain it every region,
//     making waves 0-1 arrive ~HBM-latency late and convoying all 13 waves).
//     No sched_barrier(0) — r7 showed order-pinning regresses.

__global__ __launch_bounds__(WGS)
void lstm_mfma10(const float* __restrict__ x,
                 const float* __restrict__ Wih0, const float* __restrict__ Whh0,
                 const float* __restrict__ bih0, const float* __restrict__ bhh0,
                 const float* __restrict__ Wih1, const float* __restrict__ Whh1,
                 const float* __restrict__ bih1, const float* __restrict__ bhh1,
                 const float* __restrict__ Wlin, const float* __restrict__ blin,
                 float* __restrict__ out)
{
    __shared__ __align__(16) _Float16 Bbuf[2][NKF][64][8];   // 8 KiB
    __shared__ float h1f[NB][52];

    const int tid    = threadIdx.x;
    const int w      = tid >> 6;          // wave 0..12 = M-tile
    const int l      = tid & 63;
    const int sg     = l >> 4;            // 0..3
    const int bcol   = l & 15;            // batch column
    const int batch0 = blockIdx.x * NB;

    _Float16* bbase = &Bbuf[0][0][0][0];

    // ---- zero B space (2*PARF f16 = 2048 ints) ----
    {
        int* bz = (int*)bbase;
        for (int i = tid; i < 2048; i += WGS) bz[i] = 0;
    }
    __syncthreads();

    auto baddr = [&](int k, int col) -> int {     // f16 index inside one parity buffer
        int kf = k >> 5, kl = k & 31;
        return (kf * 64 + col + (((kl >> 2) & 3) << 4)) * 8
               + ((kl & 3) | (((kl >> 4) & 1) << 2));
    };

    // ---- stage x(0)->buf[1], x(1)->buf[0] ----
    const bool xact = (tid < NB * 5);
    const int  xb = tid / 5, xd = tid % 5;
    const float* xptr = x + (size_t)(batch0 + xb) * TSTEPS * 5 + xd;
    int xadr = 0;
    if (xact) {
        xadr = baddr(50 + xd, xb);
        bbase[PARF + xadr] = (_Float16)xptr[0];   // x(0) -> buf[1]
        bbase[xadr]        = (_Float16)xptr[5];   // x(1) -> buf[0]
    }

    // ---- gather pre-scaled A fragments + biases ----
    // frag k mapping (same kappa for A and B): k = kf*32 + 4*sg + (e&3) + 16*(e>>2)
    f16x8 A0[2], A1[NKF];
    f32x4 bia0, bia1;
    float c0 = 0.f, c1 = 0.f;
    {
        const int arow = w * 16 + bcol;      // interleaved gate-row = j*4 + gate
        const int jj   = arow >> 2;
        const int gt   = arow & 3;
        const bool real = (jj < 50);
        const int row  = gt * 50 + jj;       // PyTorch gate-order row
        const float s  = (gt == 2) ? 2.885390082f : -1.442695041f;
        #pragma unroll
        for (int kf = 0; kf < 2; ++kf) {
            f16x8 a;
            #pragma unroll
            for (int e = 0; e < 8; ++e) {
                int k = kf * 32 + 4 * sg + (e & 3) + ((e >> 2) << 4);
                float v = 0.f;
                if (real) {
                    if (k < 50)      v = Whh0[row * 50 + k];
                    else if (k < 55) v = Wih0[row * 5 + (k - 50)];
                }
                a[e] = (_Float16)(s * v);
            }
            A0[kf] = a;
        }
        #pragma unroll
        for (int kf = 0; kf < NKF; ++kf) {
            f16x8 a;
            #pragma unroll
            for (int e = 0; e < 8; ++e) {
                int k = kf * 32 + 4 * sg + (e & 3) + ((e >> 2) << 4);
                float v = 0.f;
                if (real) {
                    if (k < 50)                  v = Wih1[row * 50 + k];
                    else if (k >= 56 && k < 106) v = Whh1[row * 50 + (k - 56)];
                }
                a[e] = (_Float16)(s * v);
            }
            A1[kf] = a;
        }
    }
    const int j   = 4 * w + sg;              // this lane's hidden index
    const bool jok = (j < 50);
    {
        f32x4 b0, b1;
        #pragma unroll
        for (int r = 0; r < 4; ++r) {
            const float sr = (r == 2) ? 2.885390082f : -1.442695041f;
            b0[r] = jok ? sr * (bih0[r * 50 + j] + bhh0[r * 50 + j]) : 0.f;
            b1[r] = jok ? sr * (bih1[r * 50 + j] + bhh1[r * 50 + j]) : 0.f;
        }
        bia0 = b0; bia1 = b1;
    }

    const int adrH0 = jok ? baddr(j, bcol) : 0;
    const int adrH1 = jok ? baddr(56 + j, bcol) : 0;

    // combined-rcp update: 5 exp2 + 3 rcp
    auto update = [&](const f32x4& acc, float& c, int wadr) -> float {
        float ei = __builtin_amdgcn_exp2f(acc[0]);
        float ef = __builtin_amdgcn_exp2f(acc[1]);
        float eg = __builtin_amdgcn_exp2f(acc[2]);
        float eo = __builtin_amdgcn_exp2f(acc[3]);
        float fv  = __builtin_amdgcn_rcpf(1.0f + ef);
        float igv = (eg - 1.0f) * __builtin_amdgcn_rcpf((1.0f + ei) * (1.0f + eg));
        c = fv * c + igv;
        float ec = __builtin_amdgcn_exp2f(2.885390082f * c);
        float h  = (ec - 1.0f) * __builtin_amdgcn_rcpf((1.0f + eo) * (1.0f + ec));
        if (jok) bbase[wadr] = (_Float16)h;
        return h;
    };

    const _Float16* vbase = &Bbuf[0][0][l][0];
    const f32x4 Zv = {0.f, 0.f, 0.f, 0.f};
    __syncthreads();

    // ---- prologue: A(0) on buf[1] {h0(-1)=0, x(0)}; write h0(0) -> buf[0] ----
    {
        const _Float16* rd = vbase + PARF;
        f32x4 a = bia0;
        a = __builtin_amdgcn_mfma_f32_16x16x32_f16(A0[0], *(const f16x8*)(rd), a, 0, 0, 0);
        a = __builtin_amdgcn_mfma_f32_16x16x32_f16(A0[1], *(const f16x8*)(rd + 512), a, 0, 0, 0);
        update(a, c0, adrH0);                 // -> buf[0]
    }
    float xv_next = xact ? xptr[10] : 0.f;    // x(2)
    __syncthreads();

    // ---- main loop: one region per timestep, unrolled x2 for constant parity;
    //      last pair peeled so the h1f-store check is compile-time ----
#define REGION(PAR, T, ST)                                                       \
    {                                                                            \
        float xv2 = (xact && (T) + 3 < TSTEPS) ? xptr[((T) + 3) * 5] : 0.f;      \
        const _Float16* rd = vbase + (PAR) * PARF;                               \
        const int wo = ((PAR) ^ 1) * PARF;                                       \
        f16x8 bf0 = *(const f16x8*)(rd);                                         \
        f16x8 bf1 = *(const f16x8*)(rd + 512);                                   \
        f16x8 bf2 = *(const f16x8*)(rd + 1024);                                  \
        f16x8 bf3 = *(const f16x8*)(rd + 1536);                                  \
        if (xact && (T) + 2 < TSTEPS) bbase[wo + xadr] = (_Float16)xv_next;      \
        f32x4 aB1 = bia1;                                                        \
        aB1 = __builtin_amdgcn_mfma_f32_16x16x32_f16(A1[0], bf0, aB1, 0, 0, 0);  \
        aB1 = __builtin_amdgcn_mfma_f32_16x16x32_f16(A1[1], bf1, aB1, 0, 0, 0);  \
        f32x4 aB2 = Zv;                                                          \
        aB2 = __builtin_amdgcn_mfma_f32_16x16x32_f16(A1[2], bf2, aB2, 0, 0, 0);  \
        aB2 = __builtin_amdgcn_mfma_f32_16x16x32_f16(A1[3], bf3, aB2, 0, 0, 0);  \
        f32x4 aA = bia0;                                                         \
        aA = __builtin_amdgcn_mfma_f32_16x16x32_f16(A0[0], bf0, aA, 0, 0, 0);    \
        aA = __builtin_amdgcn_mfma_f32_16x16x32_f16(A0[1], bf1, aA, 0, 0, 0);    \
        f32x4 aB = aB1 + aB2;                                                    \
        float h1v = update(aB, c1, wo + adrH1);                                  \
        update(aA, c0, wo + adrH0);                                              \
        if ((ST) && jok) h1f[bcol][j] = h1v;                                     \
        xv_next = xv2;                                                           \
        asm volatile("s_waitcnt lgkmcnt(0)" ::: "memory");                       \
        __builtin_amdgcn_s_barrier();                                            \
    }

    for (int t = 0; t < TSTEPS - 2; t += 2) {
        REGION(0, t, false)
        REGION(1, t + 1, false)
    }
    REGION(0, TSTEPS - 2, false)
    REGION(1, TSTEPS - 1, true)
#undef REGION

    __syncthreads();

    // ---- final linear: out[b] = Wlin . h1[b] + blin ----
    if (tid < NB) {
        float acc = blin[0];
        #pragma unroll 10
        for (int jj = 0; jj < 50; ++jj) acc += Wlin[jj] * h1f[tid][jj];
        out[batch0 + tid] = acc;
    }
}

extern "C" void kernel_launch(void* const* d_in, const int* in_sizes, int n_in,
                              void* d_out, int out_size, void* d_ws, size_t ws_size,
                              hipStream_t stream) {
    (void)in_sizes; (void)n_in; (void)d_ws; (void)ws_size; (void)out_size;
    const float* x    = (const float*)d_in[0];
    const float* Wih0 = (const float*)d_in[1];
    const float* Whh0 = (const float*)d_in[2];
    const float* bih0 = (const float*)d_in[3];
    const float* bhh0 = (const float*)d_in[4];
    const float* Wih1 = (const float*)d_in[5];
    const float* Whh1 = (const float*)d_in[6];
    const float* bih1 = (const float*)d_in[7];
    const float* bhh1 = (const float*)d_in[8];
    const float* Wlin = (const float*)d_in[9];
    const float* blin = (const float*)d_in[10];
    float* out = (float*)d_out;

    dim3 grid(4096 / NB);
    dim3 block(WGS);
    hipLaunchKernelGGL(lstm_mfma10, grid, block, 0, stream,
                       x, Wih0, Whh0, bih0, bhh0,
                       Wih1, Whh1, bih1, bhh1, Wlin, blin, out);
}

// Round 12
// 314.612 us; speedup vs baseline: 1.1573x; 1.1573x over previous
//
#include <hip/hip_runtime.h>

#define TSTEPS 512
#define NB     16        // batch per workgroup
#define NW     13        // waves = M-tiles (200 gate-rows -> 13 tiles of 16)
#define WGS    (NW * 64) // 832

typedef _Float16 f16x8 __attribute__((ext_vector_type(8)));
typedef float    f32x4 __attribute__((ext_vector_type(4)));

#define NKF  4           // kfrags per parity buffer (layer1 reads all 4, layer0 kf0-1)
#define PARF 2048        // f16 per parity buffer = 4*64*8

// K row space per parity buffer (4 kfrags x 32 rows = 128), single-f16 h:
//   rows  0-49 : h0(t)     rows 50-54 : x(t+1)    row 55 : pad (h0 pad-lane sink)
//   rows 56-105: h1(t-1)   rows 106-127 : pad (A = 0; h1 pad-lane sink 106/107)
// Weights pre-scaled: gates i,f,o by -log2(e); gate g by 2*log2(e).
// SINGLE-RCP cell update (this round): with u=(1+ei)(1+eg), v=(1+ef),
//   c' <- [c'*u + 2.885390*(eg-1)*v] * rcp(u*v)      (c' = 2*log2e * c_true)
//   h   = (ec-1)*rcp((1+eo)*(1+ec)),  ec = exp2(c')
//   -> 7 TRANS (5 exp2 + 2 rcp) per update, shorter c->exp2 chain.
// h stores are UNCONDITIONAL: pad lanes (j=50,51) write h0 to pad row 55 and
// h1 to rows 106/107 — all A=0 rows, so garbage there never enters a result.
//
// MERGED-REGION schedule, ONE barrier per region (= per timestep):
//   region r (p=r&1): read buf[p] = {h0(r), x(r+1), h1(r-1)}
//     B(r):   A1 x kf0-3 -> h1(r)   -> buf[p^1] rows 56-105
//     A(r+1): A0 x kf0-1 -> h0(r+1) -> buf[p^1] rows 0-49
//     xwrite: x(r+2)               -> buf[p^1] rows 50-54
//   __syncthreads()   (r11 showed the vmcnt drain here is free; asm barriers hurt)

__global__ __launch_bounds__(WGS)
void lstm_mfma11(const float* __restrict__ x,
                 const float* __restrict__ Wih0, const float* __restrict__ Whh0,
                 const float* __restrict__ bih0, const float* __restrict__ bhh0,
                 const float* __restrict__ Wih1, const float* __restrict__ Whh1,
                 const float* __restrict__ bih1, const float* __restrict__ bhh1,
                 const float* __restrict__ Wlin, const float* __restrict__ blin,
                 float* __restrict__ out)
{
    __shared__ __align__(16) _Float16 Bbuf[2][NKF][64][8];   // 8 KiB
    __shared__ float h1f[NB][52];

    const int tid    = threadIdx.x;
    const int w      = tid >> 6;          // wave 0..12 = M-tile
    const int l      = tid & 63;
    const int sg     = l >> 4;            // 0..3
    const int bcol   = l & 15;            // batch column
    const int batch0 = blockIdx.x * NB;

    _Float16* bbase = &Bbuf[0][0][0][0];

    // ---- zero B space (2*PARF f16 = 2048 ints) ----
    {
        int* bz = (int*)bbase;
        for (int i = tid; i < 2048; i += WGS) bz[i] = 0;
    }
    __syncthreads();

    auto baddr = [&](int k, int col) -> int {     // f16 index inside one parity buffer
        int kf = k >> 5, kl = k & 31;
        return (kf * 64 + col + (((kl >> 2) & 3) << 4)) * 8
               + ((kl & 3) | (((kl >> 4) & 1) << 2));
    };

    // ---- stage x(0)->buf[1], x(1)->buf[0] ----
    const bool xact = (tid < NB * 5);
    const int  xb = tid / 5, xd = tid % 5;
    const float* xptr = x + (size_t)(batch0 + xb) * TSTEPS * 5 + xd;
    int xadr = 0;
    if (xact) {
        xadr = baddr(50 + xd, xb);
        bbase[PARF + xadr] = (_Float16)xptr[0];   // x(0) -> buf[1]
        bbase[xadr]        = (_Float16)xptr[5];   // x(1) -> buf[0]
    }

    // ---- gather pre-scaled A fragments + biases ----
    // frag k mapping (same kappa for A and B): k = kf*32 + 4*sg + (e&3) + 16*(e>>2)
    f16x8 A0[2], A1[NKF];
    f32x4 bia0, bia1;
    float c0 = 0.f, c1 = 0.f;                // pre-scaled cell states (2*log2e * c)
    {
        const int arow = w * 16 + bcol;      // interleaved gate-row = j*4 + gate
        const int jj   = arow >> 2;
        const int gt   = arow & 3;
        const bool real = (jj < 50);
        const int row  = gt * 50 + jj;       // PyTorch gate-order row
        const float s  = (gt == 2) ? 2.885390082f : -1.442695041f;
        #pragma unroll
        for (int kf = 0; kf < 2; ++kf) {
            f16x8 a;
            #pragma unroll
            for (int e = 0; e < 8; ++e) {
                int k = kf * 32 + 4 * sg + (e & 3) + ((e >> 2) << 4);
                float v = 0.f;
                if (real) {
                    if (k < 50)      v = Whh0[row * 50 + k];
                    else if (k < 55) v = Wih0[row * 5 + (k - 50)];
                }
                a[e] = (_Float16)(s * v);
            }
            A0[kf] = a;
        }
        #pragma unroll
        for (int kf = 0; kf < NKF; ++kf) {
            f16x8 a;
            #pragma unroll
            for (int e = 0; e < 8; ++e) {
                int k = kf * 32 + 4 * sg + (e & 3) + ((e >> 2) << 4);
                float v = 0.f;
                if (real) {
                    if (k < 50)                  v = Wih1[row * 50 + k];
                    else if (k >= 56 && k < 106) v = Whh1[row * 50 + (k - 56)];
                }
                a[e] = (_Float16)(s * v);
            }
            A1[kf] = a;
        }
    }
    const int j   = 4 * w + sg;              // this lane's hidden index (50,51 = pad)
    const bool jok = (j < 50);
    {
        f32x4 b0, b1;
        #pragma unroll
        for (int r = 0; r < 4; ++r) {
            const float sr = (r == 2) ? 2.885390082f : -1.442695041f;
            b0[r] = jok ? sr * (bih0[r * 50 + j] + bhh0[r * 50 + j]) : 0.f;
            b1[r] = jok ? sr * (bih1[r * 50 + j] + bhh1[r * 50 + j]) : 0.f;
        }
        bia0 = b0; bia1 = b1;
    }

    // unconditional store addresses: pad lanes land on A=0 rows
    const int adrH0 = baddr(jok ? j : 55, bcol);   // rows 0-49, pad -> 55
    const int adrH1 = baddr(56 + j, bcol);          // rows 56-105, pad -> 106/107

    // single-rcp update: 5 exp2 + 2 rcp
    auto update = [&](const f32x4& acc, float& c, int wadr) -> float {
        float ei = __builtin_amdgcn_exp2f(acc[0]);
        float ef = __builtin_amdgcn_exp2f(acc[1]);
        float eg = __builtin_amdgcn_exp2f(acc[2]);
        float eo = __builtin_amdgcn_exp2f(acc[3]);
        float u  = (1.0f + ei) * (1.0f + eg);
        float v  = 1.0f + ef;
        float num = c * u + 2.885390082f * (eg - 1.0f) * v;
        c = num * __builtin_amdgcn_rcpf(u * v);
        float ec = __builtin_amdgcn_exp2f(c);
        float h  = (ec - 1.0f) * __builtin_amdgcn_rcpf((1.0f + eo) * (1.0f + ec));
        bbase[wadr] = (_Float16)h;
        return h;
    };

    const _Float16* vbase = &Bbuf[0][0][l][0];
    __syncthreads();

    // ---- prologue: A(0) on buf[1] {h0(-1)=0, x(0)}; write h0(0) -> buf[0] ----
    {
        const _Float16* rd = vbase + PARF;
        f32x4 a = bia0;
        a = __builtin_amdgcn_mfma_f32_16x16x32_f16(A0[0], *(const f16x8*)(rd), a, 0, 0, 0);
        a = __builtin_amdgcn_mfma_f32_16x16x32_f16(A0[1], *(const f16x8*)(rd + 512), a, 0, 0, 0);
        update(a, c0, adrH0);                 // -> buf[0]
    }
    float xv_next = xact ? xptr[10] : 0.f;    // x(2)
    __syncthreads();

    // ---- main loop: one region per timestep, unrolled x2 for constant parity;
    //      last pair peeled so the h1f-store check is compile-time ----
#define REGION(PAR, T, ST)                                                       \
    {                                                                            \
        const _Float16* rd = vbase + (PAR) * PARF;                               \
        const int wo = ((PAR) ^ 1) * PARF;                                       \
        f16x8 bf0 = *(const f16x8*)(rd);                                         \
        f16x8 bf1 = *(const f16x8*)(rd + 512);                                   \
        f16x8 bf2 = *(const f16x8*)(rd + 1024);                                  \
        f16x8 bf3 = *(const f16x8*)(rd + 1536);                                  \
        if (xact && (T) + 2 < TSTEPS) bbase[wo + xadr] = (_Float16)xv_next;      \
        float xv2 = (xact && (T) + 3 < TSTEPS) ? xptr[((T) + 3) * 5] : 0.f;      \
        f32x4 aB = bia1;                                                         \
        aB = __builtin_amdgcn_mfma_f32_16x16x32_f16(A1[0], bf0, aB, 0, 0, 0);    \
        aB = __builtin_amdgcn_mfma_f32_16x16x32_f16(A1[1], bf1, aB, 0, 0, 0);    \
        aB = __builtin_amdgcn_mfma_f32_16x16x32_f16(A1[2], bf2, aB, 0, 0, 0);    \
        aB = __builtin_amdgcn_mfma_f32_16x16x32_f16(A1[3], bf3, aB, 0, 0, 0);    \
        f32x4 aA = bia0;                                                         \
        aA = __builtin_amdgcn_mfma_f32_16x16x32_f16(A0[0], bf0, aA, 0, 0, 0);    \
        aA = __builtin_amdgcn_mfma_f32_16x16x32_f16(A0[1], bf1, aA, 0, 0, 0);    \
        float h1v = update(aB, c1, wo + adrH1);                                  \
        update(aA, c0, wo + adrH0);                                              \
        if ((ST)) h1f[bcol][j < 50 ? j : 50] = h1v;                              \
        xv_next = xv2;                                                           \
        __syncthreads();                                                         \
    }

    for (int t = 0; t < TSTEPS - 2; t += 2) {
        REGION(0, t, false)
        REGION(1, t + 1, false)
    }
    REGION(0, TSTEPS - 2, false)
    REGION(1, TSTEPS - 1, true)
#undef REGION

    // ---- final linear: out[b] = Wlin . h1[b] + blin ----
    if (tid < NB) {
        float acc = blin[0];
        #pragma unroll 10
        for (int jj = 0; jj < 50; ++jj) acc += Wlin[jj] * h1f[tid][jj];
        out[batch0 + tid] = acc;
    }
}

extern "C" void kernel_launch(void* const* d_in, const int* in_sizes, int n_in,
                              void* d_out, int out_size, void* d_ws, size_t ws_size,
                              hipStream_t stream) {
    (void)in_sizes; (void)n_in; (void)d_ws; (void)ws_size; (void)out_size;
    const float* x    = (const float*)d_in[0];
    const float* Wih0 = (const float*)d_in[1];
    const float* Whh0 = (const float*)d_in[2];
    const float* bih0 = (const float*)d_in[3];
    const float* bhh0 = (const float*)d_in[4];
    const float* Wih1 = (const float*)d_in[5];
    const float* Whh1 = (const float*)d_in[6];
    const float* bih1 = (const float*)d_in[7];
    const float* bhh1 = (const float*)d_in[8];
    const float* Wlin = (const float*)d_in[9];
    const float* blin = (const float*)d_in[10];
    float* out = (float*)d_out;

    dim3 grid(4096 / NB);
    dim3 block(WGS);
    hipLaunchKernelGGL(lstm_mfma11, grid, block, 0, stream,
                       x, Wih0, Whh0, bih0, bhh0,
                       Wih1, Whh1, bih1, bhh1, Wlin, blin, out);
}

// Round 13
// 312.650 us; speedup vs baseline: 1.1646x; 1.0063x over previous
//
#include <hip/hip_runtime.h>

#define TSTEPS 512
#define NB     16        // batch per workgroup
#define NW     16        // waves = M-tiles (200 gate-rows -> 13 real + 3 pad tiles; 4/4/4/4 per SIMD)
#define WGS    (NW * 64) // 1024

typedef _Float16 f16x8 __attribute__((ext_vector_type(8)));
typedef float    f32x4 __attribute__((ext_vector_type(4)));

#define NKF  4           // kfrags per parity buffer (layer1 reads all 4, layer0 kf0-1)
#define PARF 2048        // f16 per parity buffer = 4*64*8

// K row space per parity buffer (4 kfrags x 32 rows = 128), single-f16 h:
//   rows  0-49 : h0(t)     rows 50-54 : x(t+1)    row 55 : pad
//   rows 56-105: h1(t-1)   rows 106-127 : pad (A = 0)
//     pad-lane sinks: h1 -> rows 106-119, h0 -> rows 120-123 (all A=0)
// Weights pre-scaled: gates i,f,o by -log2(e); gate g by 2*log2(e).
// Single-rcp cell update (r12): u=(1+ei)(1+eg), v=(1+ef),
//   c' <- [c'*u + 2.885390*(eg-1)*v] * rcp(u*v)      (c' = 2*log2e * c_true)
//   h   = (ec-1)*rcp((1+eo)*(1+ec)),  ec = exp2(c')   -> 7 TRANS per update.
//
// MERGED-REGION schedule, ONE barrier per region (= per timestep):
//   region r (p=r&1): read buf[p] = {h0(r), x(r+1), h1(r-1)}
//     B(r):   A1 x kf0-3 -> h1(r)   -> buf[p^1] rows 56-105
//     A(r+1): A0 x kf0-1 -> h0(r+1) -> buf[p^1] rows 0-49
//     xwrite: x(r+2)               -> buf[p^1] rows 50-54
//   __syncthreads()
// THIS ROUND (isolated change): NW 13 -> 16. Balanced 4 waves/SIMD (was 4/3/3/3)
// and +23% TLP for latency hiding; pad waves' A=0 fragments make their updates
// value-irrelevant (sink rows above).

__global__ __launch_bounds__(WGS)
void lstm_mfma12(const float* __restrict__ x,
                 const float* __restrict__ Wih0, const float* __restrict__ Whh0,
                 const float* __restrict__ bih0, const float* __restrict__ bhh0,
                 const float* __restrict__ Wih1, const float* __restrict__ Whh1,
                 const float* __restrict__ bih1, const float* __restrict__ bhh1,
                 const float* __restrict__ Wlin, const float* __restrict__ blin,
                 float* __restrict__ out)
{
    __shared__ __align__(16) _Float16 Bbuf[2][NKF][64][8];   // 8 KiB
    __shared__ float h1f[NB][52];

    const int tid    = threadIdx.x;
    const int w      = tid >> 6;          // wave 0..15 = M-tile
    const int l      = tid & 63;
    const int sg     = l >> 4;            // 0..3
    const int bcol   = l & 15;            // batch column
    const int batch0 = blockIdx.x * NB;

    _Float16* bbase = &Bbuf[0][0][0][0];

    // ---- zero B space (2*PARF f16 = 2048 ints) ----
    {
        int* bz = (int*)bbase;
        for (int i = tid; i < 2048; i += WGS) bz[i] = 0;
    }
    __syncthreads();

    auto baddr = [&](int k, int col) -> int {     // f16 index inside one parity buffer
        int kf = k >> 5, kl = k & 31;
        return (kf * 64 + col + (((kl >> 2) & 3) << 4)) * 8
               + ((kl & 3) | (((kl >> 4) & 1) << 2));
    };

    // ---- stage x(0)->buf[1], x(1)->buf[0] ----
    const bool xact = (tid < NB * 5);
    const int  xb = tid / 5, xd = tid % 5;
    const float* xptr = x + (size_t)(batch0 + xb) * TSTEPS * 5 + xd;
    int xadr = 0;
    if (xact) {
        xadr = baddr(50 + xd, xb);
        bbase[PARF + xadr] = (_Float16)xptr[0];   // x(0) -> buf[1]
        bbase[xadr]        = (_Float16)xptr[5];   // x(1) -> buf[0]
    }

    // ---- gather pre-scaled A fragments + biases ----
    // frag k mapping (same kappa for A and B): k = kf*32 + 4*sg + (e&3) + 16*(e>>2)
    f16x8 A0[2], A1[NKF];
    f32x4 bia0, bia1;
    float c0 = 0.f, c1 = 0.f;                // pre-scaled cell states (2*log2e * c)
    {
        const int arow = w * 16 + bcol;      // interleaved gate-row = j*4 + gate
        const int jj   = arow >> 2;
        const int gt   = arow & 3;
        const bool real = (jj < 50);
        const int row  = gt * 50 + jj;       // PyTorch gate-order row
        const float s  = (gt == 2) ? 2.885390082f : -1.442695041f;
        #pragma unroll
        for (int kf = 0; kf < 2; ++kf) {
            f16x8 a;
            #pragma unroll
            for (int e = 0; e < 8; ++e) {
                int k = kf * 32 + 4 * sg + (e & 3) + ((e >> 2) << 4);
                float v = 0.f;
                if (real) {
                    if (k < 50)      v = Whh0[row * 50 + k];
                    else if (k < 55) v = Wih0[row * 5 + (k - 50)];
                }
                a[e] = (_Float16)(s * v);
            }
            A0[kf] = a;
        }
        #pragma unroll
        for (int kf = 0; kf < NKF; ++kf) {
            f16x8 a;
            #pragma unroll
            for (int e = 0; e < 8; ++e) {
                int k = kf * 32 + 4 * sg + (e & 3) + ((e >> 2) << 4);
                float v = 0.f;
                if (real) {
                    if (k < 50)                  v = Wih1[row * 50 + k];
                    else if (k >= 56 && k < 106) v = Whh1[row * 50 + (k - 56)];
                }
                a[e] = (_Float16)(s * v);
            }
            A1[kf] = a;
        }
    }
    const int j   = 4 * w + sg;              // this lane's hidden index (>=50 = pad)
    const bool jok = (j < 50);
    {
        f32x4 b0, b1;
        #pragma unroll
        for (int r = 0; r < 4; ++r) {
            const float sr = (r == 2) ? 2.885390082f : -1.442695041f;
            b0[r] = jok ? sr * (bih0[r * 50 + j] + bhh0[r * 50 + j]) : 0.f;
            b1[r] = jok ? sr * (bih1[r * 50 + j] + bhh1[r * 50 + j]) : 0.f;
        }
        bia0 = b0; bia1 = b1;
    }

    // unconditional store addresses: pad lanes land on A=0 rows
    const int adrH0 = baddr(jok ? j : (120 + (j & 3)), bcol);  // pad -> rows 120-123
    const int adrH1 = baddr(jok ? (56 + j) : (106 + (j - 50)), bcol); // pad -> 106-119

    // single-rcp update: 5 exp2 + 2 rcp
    auto update = [&](const f32x4& acc, float& c, int wadr) -> float {
        float ei = __builtin_amdgcn_exp2f(acc[0]);
        float ef = __builtin_amdgcn_exp2f(acc[1]);
        float eg = __builtin_amdgcn_exp2f(acc[2]);
        float eo = __builtin_amdgcn_exp2f(acc[3]);
        float u  = (1.0f + ei) * (1.0f + eg);
        float v  = 1.0f + ef;
        float num = c * u + 2.885390082f * (eg - 1.0f) * v;
        c = num * __builtin_amdgcn_rcpf(u * v);
        float ec = __builtin_amdgcn_exp2f(c);
        float h  = (ec - 1.0f) * __builtin_amdgcn_rcpf((1.0f + eo) * (1.0f + ec));
        bbase[wadr] = (_Float16)h;
        return h;
    };

    const _Float16* vbase = &Bbuf[0][0][l][0];
    __syncthreads();

    // ---- prologue: A(0) on buf[1] {h0(-1)=0, x(0)}; write h0(0) -> buf[0] ----
    {
        const _Float16* rd = vbase + PARF;
        f32x4 a = bia0;
        a = __builtin_amdgcn_mfma_f32_16x16x32_f16(A0[0], *(const f16x8*)(rd), a, 0, 0, 0);
        a = __builtin_amdgcn_mfma_f32_16x16x32_f16(A0[1], *(const f16x8*)(rd + 512), a, 0, 0, 0);
        update(a, c0, adrH0);                 // -> buf[0]
    }
    float xv_next = xact ? xptr[10] : 0.f;    // x(2)
    __syncthreads();

    // ---- main loop: one region per timestep, unrolled x2 for constant parity;
    //      last pair peeled so the h1f-store check is compile-time ----
#define REGION(PAR, T, ST)                                                       \
    {                                                                            \
        const _Float16* rd = vbase + (PAR) * PARF;                               \
        const int wo = ((PAR) ^ 1) * PARF;                                       \
        f16x8 bf0 = *(const f16x8*)(rd);                                         \
        f16x8 bf1 = *(const f16x8*)(rd + 512);                                   \
        f16x8 bf2 = *(const f16x8*)(rd + 1024);                                  \
        f16x8 bf3 = *(const f16x8*)(rd + 1536);                                  \
        if (xact && (T) + 2 < TSTEPS) bbase[wo + xadr] = (_Float16)xv_next;      \
        float xv2 = (xact && (T) + 3 < TSTEPS) ? xptr[((T) + 3) * 5] : 0.f;      \
        f32x4 aB = bia1;                                                         \
        aB = __builtin_amdgcn_mfma_f32_16x16x32_f16(A1[0], bf0, aB, 0, 0, 0);    \
        aB = __builtin_amdgcn_mfma_f32_16x16x32_f16(A1[1], bf1, aB, 0, 0, 0);    \
        aB = __builtin_amdgcn_mfma_f32_16x16x32_f16(A1[2], bf2, aB, 0, 0, 0);    \
        aB = __builtin_amdgcn_mfma_f32_16x16x32_f16(A1[3], bf3, aB, 0, 0, 0);    \
        f32x4 aA = bia0;                                                         \
        aA = __builtin_amdgcn_mfma_f32_16x16x32_f16(A0[0], bf0, aA, 0, 0, 0);    \
        aA = __builtin_amdgcn_mfma_f32_16x16x32_f16(A0[1], bf1, aA, 0, 0, 0);    \
        float h1v = update(aB, c1, wo + adrH1);                                  \
        update(aA, c0, wo + adrH0);                                              \
        if ((ST)) h1f[bcol][j < 50 ? j : 50] = h1v;                              \
        xv_next = xv2;                                                           \
        __syncthreads();                                                         \
    }

    for (int t = 0; t < TSTEPS - 2; t += 2) {
        REGION(0, t, false)
        REGION(1, t + 1, false)
    }
    REGION(0, TSTEPS - 2, false)
    REGION(1, TSTEPS - 1, true)
#undef REGION

    // ---- final linear: out[b] = Wlin . h1[b] + blin ----
    if (tid < NB) {
        float acc = blin[0];
        #pragma unroll 10
        for (int jj = 0; jj < 50; ++jj) acc += Wlin[jj] * h1f[tid][jj];
        out[batch0 + tid] = acc;
    }
}

extern "C" void kernel_launch(void* const* d_in, const int* in_sizes, int n_in,
                              void* d_out, int out_size, void* d_ws, size_t ws_size,
                              hipStream_t stream) {
    (void)in_sizes; (void)n_in; (void)d_ws; (void)ws_size; (void)out_size;
    const float* x    = (const float*)d_in[0];
    const float* Wih0 = (const float*)d_in[1];
    const float* Whh0 = (const float*)d_in[2];
    const float* bih0 = (const float*)d_in[3];
    const float* bhh0 = (const float*)d_in[4];
    const float* Wih1 = (const float*)d_in[5];
    const float* Whh1 = (const float*)d_in[6];
    const float* bih1 = (const float*)d_in[7];
    const float* bhh1 = (const float*)d_in[8];
    const float* Wlin = (const float*)d_in[9];
    const float* blin = (const float*)d_in[10];
    float* out = (float*)d_out;

    dim3 grid(4096 / NB);
    dim3 block(WGS);
    hipLaunchKernelGGL(lstm_mfma12, grid, block, 0, stream,
                       x, Wih0, Whh0, bih0, bhh0,
                       Wih1, Whh1, bih1, bhh1, Wlin, blin, out);
}